// Round 1
// baseline (1118.349 us; speedup 1.0000x reference)
//
#include <hip/hip_runtime.h>
#include <hip/hip_bf16.h>

#define NSTEPS 100

__device__ __forceinline__ float bf16lo_to_f(unsigned int u) {
    union { unsigned int i; float f; } c; c.i = u << 16; return c.f;
}
__device__ __forceinline__ float bf16hi_to_f(unsigned int u) {
    union { unsigned int i; float f; } c; c.i = u & 0xffff0000u; return c.f;
}
__device__ __forceinline__ unsigned short f_to_bf16_rne(float f) {
    union { float f; unsigned int i; } c; c.f = f;
    unsigned int u = c.i;
    u += 0x7fffu + ((u >> 16) & 1u);   // round-to-nearest-even
    return (unsigned short)(u >> 16);
}

// K fp32 -> bf16, 4 elements/thread, fully coalesced (16B load, 8B store)
__global__ __launch_bounds__(256) void k_cvt(const float4* __restrict__ K4,
                                             ushort4* __restrict__ Kb4, int n4) {
    int i = blockIdx.x * 256 + threadIdx.x;
    if (i < n4) {
        float4 v = K4[i];
        ushort4 o;
        o.x = f_to_bf16_rne(v.x);
        o.y = f_to_bf16_rne(v.y);
        o.z = f_to_bf16_rne(v.z);
        o.w = f_to_bf16_rne(v.w);
        Kb4[i] = o;
    }
}

// One wave per row: dot(K[row,:], zr) and dot(K[row,:], zi) in one pass,
// then the per-row ODE update + disc clamp. z double-buffered across launches.
__device__ __forceinline__ void row_update(int row, float sr, float si,
                                           const float2* __restrict__ zin,
                                           float2* __restrict__ zout,
                                           float omega, float dt, float inv2n) {
    float u = sr, v = si;                 // S = (u,-v), T = (u,v)
    float2 zc = zin[row];
    float x = zc.x, y = zc.y;
    float A = x * x - y * y;              // Re(z^2)
    float B = 2.0f * x * y;               // Im(z^2)
    float dzr = inv2n * (u - (u * A + v * B)) + omega * x;
    float dzi = inv2n * (v - (u * B - v * A)) + omega * y;
    float nx = x + dt * dzr;
    float ny = y + dt * dzi;
    float a2 = nx * nx + ny * ny;
    if (a2 >= 0.999f * 0.999f) {
        float s = 0.999f / sqrtf(a2);
        nx *= s; ny *= s;
    }
    zout[row] = make_float2(nx, ny);
}

__global__ __launch_bounds__(256) void k_step_bf16(
    const unsigned short* __restrict__ Kb, const float2* __restrict__ zin,
    float2* __restrict__ zout, const float* __restrict__ omega_p,
    const float* __restrict__ dt_p, int n) {
    const int wave = threadIdx.x >> 6;
    const int lane = threadIdx.x & 63;
    const int row  = blockIdx.x * 4 + wave;
    const uint4* Krow = (const uint4*)(Kb + (long long)row * n);   // 8 bf16 / 16B
    const float4* z4 = (const float4*)zin;                         // 2 complex / 16B
    float sr = 0.0f, si = 0.0f;
    const int iters = n >> 9;            // 512 cols per wave-iter
    for (int it = 0; it < iters; ++it) {
        int c8 = it * 64 + lane;         // 8-col group index (coalesced)
        uint4 k = Krow[c8];
        float4 z0 = z4[c8 * 4 + 0];
        float4 z1 = z4[c8 * 4 + 1];
        float4 z2 = z4[c8 * 4 + 2];
        float4 z3 = z4[c8 * 4 + 3];
        float k0 = bf16lo_to_f(k.x), k1 = bf16hi_to_f(k.x);
        float k2 = bf16lo_to_f(k.y), k3 = bf16hi_to_f(k.y);
        float k4 = bf16lo_to_f(k.z), k5 = bf16hi_to_f(k.z);
        float k6 = bf16lo_to_f(k.w), k7 = bf16hi_to_f(k.w);
        sr += k0 * z0.x + k1 * z0.z + k2 * z1.x + k3 * z1.z
            + k4 * z2.x + k5 * z2.z + k6 * z3.x + k7 * z3.z;
        si += k0 * z0.y + k1 * z0.w + k2 * z1.y + k3 * z1.w
            + k4 * z2.y + k5 * z2.w + k6 * z3.y + k7 * z3.w;
    }
#pragma unroll
    for (int off = 32; off; off >>= 1) {
        sr += __shfl_down(sr, off, 64);
        si += __shfl_down(si, off, 64);
    }
    if (lane == 0) {
        row_update(row, sr, si, zin, zout, *omega_p, *dt_p, 1.0f / (2.0f * n));
    }
}

__global__ __launch_bounds__(256) void k_step_f32(
    const float* __restrict__ K, const float2* __restrict__ zin,
    float2* __restrict__ zout, const float* __restrict__ omega_p,
    const float* __restrict__ dt_p, int n) {
    const int wave = threadIdx.x >> 6;
    const int lane = threadIdx.x & 63;
    const int row  = blockIdx.x * 4 + wave;
    const float4* Krow = (const float4*)(K + (long long)row * n);
    const float4* z4 = (const float4*)zin;
    float sr = 0.0f, si = 0.0f;
    const int iters = n >> 8;            // 256 cols per wave-iter
    for (int it = 0; it < iters; ++it) {
        int c4 = it * 64 + lane;
        float4 k = Krow[c4];
        float4 z0 = z4[c4 * 2 + 0];
        float4 z1 = z4[c4 * 2 + 1];
        sr += k.x * z0.x + k.y * z0.z + k.z * z1.x + k.w * z1.z;
        si += k.x * z0.y + k.y * z0.w + k.z * z1.y + k.w * z1.w;
    }
#pragma unroll
    for (int off = 32; off; off >>= 1) {
        sr += __shfl_down(sr, off, 64);
        si += __shfl_down(si, off, 64);
    }
    if (lane == 0) {
        row_update(row, sr, si, zin, zout, *omega_p, *dt_p, 1.0f / (2.0f * n));
    }
}

extern "C" void kernel_launch(void* const* d_in, const int* in_sizes, int n_in,
                              void* d_out, int out_size, void* d_ws, size_t ws_size,
                              hipStream_t stream) {
    const float2* z0      = (const float2*)d_in[0];
    const float*  K       = (const float*)d_in[1];
    const float*  omega_p = (const float*)d_in[2];
    const float*  dt_p    = (const float*)d_in[3];
    const int n = in_sizes[0] / 2;       // 4096
    float2* out = (float2*)d_out;

    const size_t kb_bytes = (size_t)n * (size_t)n * 2;                 // bf16 K
    const size_t need     = kb_bytes + 2 * (size_t)n * sizeof(float2); // + 2 z bufs
    const int nblocks = n / 4;           // 4 rows (waves) per 256-thread block

    if (ws_size >= need) {
        unsigned short* Kb = (unsigned short*)d_ws;
        float2* zbuf0 = (float2*)((char*)d_ws + kb_bytes);
        float2* zbuf1 = zbuf0 + n;
        int n4 = (n / 4) * n;            // float4 count of K
        k_cvt<<<(n4 + 255) / 256, 256, 0, stream>>>((const float4*)K,
                                                    (ushort4*)d_ws, n4);
        const float2* cur = z0;
        for (int s = 0; s < NSTEPS; ++s) {
            float2* nxt = (s == NSTEPS - 1) ? out : ((s & 1) ? zbuf1 : zbuf0);
            k_step_bf16<<<nblocks, 256, 0, stream>>>(Kb, cur, nxt, omega_p, dt_p, n);
            cur = nxt;
        }
    } else {
        float2* zbuf0 = (float2*)d_ws;
        float2* zbuf1 = zbuf0 + n;
        const float2* cur = z0;
        for (int s = 0; s < NSTEPS; ++s) {
            float2* nxt = (s == NSTEPS - 1) ? out : ((s & 1) ? zbuf1 : zbuf0);
            k_step_f32<<<nblocks, 256, 0, stream>>>(K, cur, nxt, omega_p, dt_p, n);
            cur = nxt;
        }
    }
}